// Round 12
// baseline (329.307 us; speedup 1.0000x reference)
//
#include <hip/hip_runtime.h>
#include <hip/hip_bf16.h>

// ---- types / helpers -------------------------------------------------------
typedef __attribute__((ext_vector_type(8))) short short8;
typedef __attribute__((ext_vector_type(4))) short short4v;
typedef __attribute__((ext_vector_type(4))) float float4v;
typedef __bf16 bf16x8 __attribute__((ext_vector_type(8)));

#define MFMA16(A,B,C) __builtin_amdgcn_mfma_f32_16x16x32_bf16( \
    __builtin_bit_cast(bf16x8,(A)), __builtin_bit_cast(bf16x8,(B)), (C), 0, 0, 0)

static __device__ __forceinline__ float bf2f(unsigned short b){
  unsigned u = ((unsigned)b) << 16; float f; __builtin_memcpy(&f,&u,sizeof(f)); return f;
}
// native RNE convert: compiler emits v_cvt_pk_bf16_f32
static __device__ __forceinline__ unsigned short f2bf(float f){
  __bf16 h = (__bf16)f;
  return __builtin_bit_cast(unsigned short, h);
}
static __device__ __forceinline__ float siluf(float x){
  return x * __builtin_amdgcn_rcpf(1.0f + __expf(-x));
}
static __device__ __forceinline__ float ldf(const float* p, size_t i){ return p[i]; }
static __device__ __forceinline__ float ldf(const unsigned short* p, size_t i){ return bf2f(p[i]); }

// ---- weight packing into fragment order ------------------------------------
template<typename T>
static __device__ __forceinline__ void pack_tile(
    const T* W, int ldw, int Krows, int Ncols,
    unsigned short* dst, int NTtot, int ntoff, int kt, int nt,
    const float* addrow, int lane)
{
  int l15 = lane & 15, q = lane >> 4;
  int col = nt * 16 + l15;
  int kr0 = kt * 32 + q * 8;
  short8 v;
  #pragma unroll
  for (int j = 0; j < 8; ++j){
    int r = kr0 + j;
    float x = 0.0f;
    if (r < Krows && col < Ncols){
      x = ldf(W, (size_t)r * ldw + col);
      if (addrow) x += addrow[(r >> 5) * 256 + col];
    }
    v[j] = (short)f2bf(x);
  }
  ((short8*)dst)[(size_t)(kt * NTtot + ntoff + nt) * 64 + lane] = v;
}

static __device__ __forceinline__ void packW_dispatch(
    int b, int lane,
    const float* Ws, const float* Wn,
    const float* typeW, const float* polarW, const float* fracW,
    const float* m1W, const float* m2W, const float* a1W, const float* a2W,
    unsigned short* Wsp, unsigned short* Wnp, unsigned short* typep,
    unsigned short* polarp, unsigned short* fracp,
    unsigned short* W12p, unsigned short* W1botp, unsigned short* W2Tp,
    unsigned short* a1p, unsigned short* a2p)
{
  if (b < 64)      { pack_tile(Ws,    256, 100, 256, Wsp,   16, 0, b >> 4, b & 15, nullptr, lane); return; }
  if (b < 256){ int s = b - 64;  pack_tile(Wn,    256, 384, 256, Wnp,   16, 0, s >> 4, s & 15, nullptr, lane); return; }
  if (b < 312){ int s = b - 256; pack_tile(typeW, 100, 256, 100, typep,  7, 0, s / 7,  s % 7,  nullptr, lane); return; }
  if (b < 320){ int s = b - 312; pack_tile(polarW,  6, 256,   6, polarp, 1, 0, s, 0, nullptr, lane); return; }
  if (b < 328){ int s = b - 320; pack_tile(fracW,   3, 256,   3, fracp,  1, 0, s, 0, nullptr, lane); return; }
  int s2 = b - 328;                   // 3200 layer-pack tiles
  int l = s2 / 800, bb = s2 % 800;
  const float* m1Wl = m1W + (size_t)l * 578 * 256;
  const float* m2Wl = m2W + (size_t)l * 65536;
  const float* a1Wl = a1W + (size_t)l * 131072;
  const float* a2Wl = a2W + (size_t)l * 65536;
  unsigned short* W12pl   = W12p   + (size_t)l * 131072;
  unsigned short* W1botpl = W1botp + (size_t)l * 16384;
  unsigned short* W2Tpl   = W2Tp   + (size_t)l * 65536;
  unsigned short* a1pl    = a1p    + (size_t)l * 131072;
  unsigned short* a2pl    = a2p    + (size_t)l * 65536;
  if (bb < 128)       pack_tile(m1Wl,           256, 256, 256, W12pl,  32,  0, bb >> 4, bb & 15, nullptr, lane);
  else if (bb < 256){ int s = bb - 128; pack_tile(m1Wl + 256*256, 256, 256, 256, W12pl,  32, 16, s >> 4, s & 15, nullptr, lane); }
  else if (bb < 288){ int s = bb - 256; pack_tile(m1Wl + 512*256, 256,  64, 256, W1botpl,16,  0, s >> 4, s & 15, nullptr, lane); }
  else if (bb < 416){ int s = bb - 288; pack_tile(m2Wl,           256, 256, 256, W2Tpl,  16,  0, s >> 4, s & 15, nullptr, lane); }
  else if (bb < 672){ int s = bb - 416; pack_tile(a1Wl,           256, 512, 256, a1pl,   16,  0, s >> 4, s & 15, nullptr, lane); }
  else              { int s = bb - 672; pack_tile(a2Wl,           256, 256, 256, a2pl,   16,  0, s >> 4, s & 15, nullptr, lane); }
}

// ---- preprocessing: weight packing + femb + lpw -----------------------------
__global__ void k_prep(
    const float* Ws, const float* Wn,
    const float* typeW, const float* polarW, const float* fracW,
    const float* m1W, const float* m2W, const float* a1W, const float* a2W,
    unsigned short* Wsp, unsigned short* Wnp, unsigned short* typep,
    unsigned short* polarp, unsigned short* fracp,
    unsigned short* W12p, unsigned short* W1botp, unsigned short* W2Tp,
    unsigned short* a1p, unsigned short* a2p,
    const float* fc, const float* lpol, const float* m1b,
    unsigned short* femb, float* lpw)
{
  int b0 = blockIdx.x;
  if (b0 < 882){
    int tile = b0 * 4 + (threadIdx.x >> 6);
    packW_dispatch(tile, threadIdx.x & 63, Ws, Wn, typeW, polarW, fracW,
                   m1W, m2W, a1W, a2W, Wsp, Wnp, typep, polarp, fracp,
                   W12p, W1botp, W2Tp, a1p, a2p);
    return;
  }
  int b = b0 - 882;
  if (b < 512){
    int e = b * 256 + threadIdx.x;             // E = 131072
    int g = e >> 10, i = (e >> 5) & 31, j = e & 31;
    int nt = g * 32 + i, ns = g * 32 + j;
    unsigned short o[64];
    #pragma unroll
    for (int k = 0; k < 3; ++k){
      float d = fc[ns * 3 + k] - fc[nt * 3 + k];
      d -= floorf(d);
      #pragma unroll
      for (int f = 0; f < 10; ++f){
        float ang = d * (6.283185307179586f * (float)f);
        o[k * 10 + f]      = f2bf(__sinf(ang));
        o[30 + k * 10 + f] = f2bf(__cosf(ang));
      }
    }
    #pragma unroll
    for (int z = 60; z < 64; ++z) o[z] = 0;
    // fragment-block layout write (v11)
    short8* dst = (short8*)femb;
    int eb = e >> 4, l15e = e & 15;
    #pragma unroll
    for (int ks = 0; ks < 2; ++ks)
      #pragma unroll
      for (int qq = 0; qq < 4; ++qq){
        short8 s;
        #pragma unroll
        for (int j2 = 0; j2 < 8; ++j2) s[j2] = (short)o[(ks*4+qq)*8 + j2];
        dst[((size_t)(eb*2 + ks))*64 + qq*16 + l15e] = s;
      }
  } else {
    int s = b - 512;
    int l = s >> 7, g = s & 127, c = threadIdx.x;
    const float* W = m1W + (size_t)l * 578 * 256;
    float acc = m1b[l * 256 + c];
    #pragma unroll
    for (int k = 0; k < 6; ++k)
      acc += lpol[g * 6 + k] * W[(572 + k) * 256 + c];
    lpw[((size_t)l * 128 + g) * 256 + c] = acc;
  }
}

#define HLD 264   // LDS row stride (shorts) for 256-col bf16 tiles

// ---- fused embedding pipeline (v15: 16 waves, grid-limited occupancy 2x) ---
// 256 blocks x 1024 thr. Same math, tiles redistributed 1-per-wave: GEMM1
// te (4 MFMA/wave), GEMM2 nf0 (12), LN row w, P GEMM tiles w*2,w*2+1 (16).
// No redundant work; bit-exact (same kt order per output tile).
__global__ __launch_bounds__(1024) void k_embed(
    const float* __restrict__ at, const float* __restrict__ t,
    const unsigned short* __restrict__ Wsp, const float* __restrict__ bs,
    const unsigned short* __restrict__ Wnp, const float* __restrict__ bn,
    const float* __restrict__ lng, const float* __restrict__ lnb,
    const unsigned short* __restrict__ W12p, const float* __restrict__ lpwl,
    float* __restrict__ nf, unsigned short* __restrict__ cat2w,
    unsigned short* __restrict__ P1, unsigned short* __restrict__ P2)
{
  __shared__ unsigned short at_s[16 * 136];    // 4.4 KB
  __shared__ unsigned short cat1_s[16 * 392];  // 12.5 KB
  __shared__ float nf32[16 * 260];             // 16.6 KB
  __shared__ unsigned short sh[16 * HLD];      // 8.4 KB
  const int w = threadIdx.x >> 6, lane = threadIdx.x & 63;
  const int l15 = lane & 15, q = lane >> 4;
  const int r0 = blockIdx.x * 16, g = blockIdx.x >> 1;
  // stage at rows (bf16, pad to 128 cols); time emb -> cat1_s cols 256..383
  if (threadIdx.x < 256){
    int row = threadIdx.x & 15, c0 = (threadIdx.x >> 4) * 8;
    #pragma unroll
    for (int j = 0; j < 8; ++j){
      int c = c0 + j;
      at_s[row*136 + c] = (c < 100) ? f2bf(at[(size_t)(r0+row)*100 + c])
                                    : (unsigned short)0;
    }
    if (threadIdx.x < 128){
      int i = threadIdx.x;
      float tg = t[g];
      int f = i & 63;
      float fr = __expf((-9.210340371976184f / 63.0f) * (float)f);
      float arg = tg * fr;
      float v = (i < 64) ? __sinf(arg) : __cosf(arg);
      unsigned short hv = f2bf(v);
      for (int n = 0; n < 16; ++n) cat1_s[n*392 + 256 + i] = hv;
    }
  }
  __syncthreads();
  // GEMM1: te = at_pad @ Ws + bs -> cat1_s[:, 0:256]; wave w -> col tile w
  {
    float4v acc = {};
    const short8* pb = (const short8*)Wsp;
    for (int kt = 0; kt < 4; ++kt){
      short8 a0 = *(const short8*)(&at_s[l15*136 + kt*32 + q*8]);
      short8 bfr = pb[(size_t)(kt*16 + w)*64 + lane];
      acc = MFMA16(a0, bfr, acc);
    }
    int c = w*16 + l15;
    float bv = bs[c];
    #pragma unroll
    for (int r = 0; r < 4; ++r)
      cat1_s[(q*4+r)*392 + c] = f2bf(acc[r] + bv);
  }
  __syncthreads();
  // GEMM2: nf0 = cat1 @ Wn + bn; wave w -> col tile w
  {
    float4v acc = {};
    const short8* pb = (const short8*)Wnp;
    for (int kt = 0; kt < 12; ++kt){
      short8 a0 = *(const short8*)(&cat1_s[l15*392 + kt*32 + q*8]);
      short8 bfr = pb[(size_t)(kt*16 + w)*64 + lane];
      acc = MFMA16(a0, bfr, acc);
    }
    int c = w*16 + l15;
    float bv = bn[c];
    #pragma unroll
    for (int r = 0; r < 4; ++r){
      int row = r0 + q*4 + r;
      float v = acc[r] + bv;
      nf[(size_t)row*256 + c] = v;
      cat2w[(size_t)row*512 + c] = f2bf(v);
      nf32[(q*4+r)*260 + c] = v;
    }
  }
  __syncthreads();
  // LN layer-0: wave w -> row w
  {
    int row = w;
    float4v x = *(const float4v*)(&nf32[row*260 + lane*4]);
    float s = x[0]+x[1]+x[2]+x[3];
    #pragma unroll
    for (int m=1;m<64;m<<=1) s += __shfl_xor(s,m,64);
    float mu = s * (1.f/256.f);
    float d0=x[0]-mu,d1=x[1]-mu,d2=x[2]-mu,d3=x[3]-mu;
    float vs=d0*d0+d1*d1+d2*d2+d3*d3;
    #pragma unroll
    for (int m=1;m<64;m<<=1) vs += __shfl_xor(vs,m,64);
    float rs = rsqrtf(vs*(1.f/256.f)+1e-5f);
    float4v gg = *(const float4v*)(lng + lane*4);
    float4v bb = *(const float4v*)(lnb + lane*4);
    short4v o;
    o[0]=(short)f2bf(d0*rs*gg[0]+bb[0]);
    o[1]=(short)f2bf(d1*rs*gg[1]+bb[1]);
    o[2]=(short)f2bf(d2*rs*gg[2]+bb[2]);
    o[3]=(short)f2bf(d3*rs*gg[3]+bb[3]);
    *(short4v*)(&sh[row*HLD + lane*4]) = o;
  }
  __syncthreads();
  // P GEMM: wave w -> packed tiles w*2, w*2+1
  float4v pc[2] = {};
  const short8* pb = (const short8*)W12p;
  for (int kt = 0; kt < 8; ++kt){
    short8 a0 = *(const short8*)(&sh[(size_t)l15*HLD + kt*32 + q*8]);
    #pragma unroll
    for (int i = 0; i < 2; ++i){
      short8 bfr = pb[(size_t)(kt*32 + w*2 + i)*64 + lane];
      pc[i] = MFMA16(a0, bfr, pc[i]);
    }
  }
  #pragma unroll
  for (int i = 0; i < 2; ++i){
    int nt = w*2 + i;
    unsigned short* dst = (nt < 16) ? P1 : P2;
    int ch = (nt & 15)*16 + l15;
    float lv = (nt < 16) ? lpwl[g*256 + ch] : 0.0f;
    #pragma unroll
    for (int r = 0; r < 4; ++r){
      int node = r0 + q*4 + r;
      dst[(size_t)node*256 + ch] = f2bf(pc[i][r] + lv);
    }
  }
}

// ---- fused a1+a2 epilogue MLP + next-layer LN + P GEMM (v15: 16 waves) -----
// 256 blocks x 1024 thr (was 512): grid-limited 1 block/CU, so waves/CU
// 8 -> 16 (50% occupancy). Tiles redistributed 1-per-wave, no redundancy:
// GEMM1 tile w (16 MFMA), GEMM2 tile w (8), LN row w, P tiles w*2..+1 (16).
__global__ __launch_bounds__(1024) void k_a12P(
    const unsigned short* __restrict__ cat2,
    const unsigned short* __restrict__ a1pl, const float* __restrict__ a1bl,
    const unsigned short* __restrict__ a2pl, const float* __restrict__ a2bl,
    float* __restrict__ nf, unsigned short* __restrict__ cat2w,
    const float* __restrict__ lng, const float* __restrict__ lnb,
    const unsigned short* __restrict__ W12p, const float* __restrict__ lpwl,
    unsigned short* __restrict__ P1, unsigned short* __restrict__ P2, int doP)
{
  __shared__ float nf32[16 * 260];          // 16.6 KB (new nf rows, f32)
  __shared__ unsigned short sh[16 * HLD];   // 8.4 KB: t1, then LN'd h (aliased)
  const int w = threadIdx.x >> 6, lane = threadIdx.x & 63;
  const int l15 = lane & 15, q = lane >> 4;
  const int r0 = blockIdx.x * 16;
  const int g = blockIdx.x >> 1;
  const short8* pb1 = (const short8*)a1pl;
  const short8* pb2 = (const short8*)a2pl;
  // GEMM1: t1 = silu(cat2 @ a1W + b1); wave w -> col tile w
  {
    float4v acc = {};
    for (int kt = 0; kt < 16; ++kt){
      short8 a0 = *(const short8*)(cat2 + (size_t)(r0 + l15)*512 + kt*32 + q*8);
      short8 bfr = pb1[(size_t)(kt*16 + w)*64 + lane];
      acc = MFMA16(a0, bfr, acc);
    }
    int c = w*16 + l15;
    float bv = a1bl[c];
    #pragma unroll
    for (int r = 0; r < 4; ++r)
      sh[(size_t)(q*4 + r)*HLD + c] = f2bf(siluf(acc[r] + bv));
  }
  __syncthreads();
  // GEMM2: c2 = t1 @ a2W; wave w -> col tile w
  {
    float4v c2v = {};
    for (int kt = 0; kt < 8; ++kt){
      short8 a0 = *(const short8*)(&sh[(size_t)l15*HLD + kt*32 + q*8]);
      short8 bfr = pb2[(size_t)(kt*16 + w)*64 + lane];
      c2v = MFMA16(a0, bfr, c2v);
    }
    // epilogue: v = nf + silu(c2 + b2)
    int c = w*16 + l15;
    float bv = a2bl[c];
    #pragma unroll
    for (int r = 0; r < 4; ++r){
      int row = r0 + q*4 + r;
      float v = nf[(size_t)row*256 + c] + siluf(c2v[r] + bv);
      nf[(size_t)row*256 + c] = v;
      cat2w[(size_t)row*512 + c] = f2bf(v);
      nf32[(q*4 + r)*260 + c] = v;
    }
  }
  if (!doP) return;
  __syncthreads();
  // LN_{l+1}: wave w -> row w -> sh (t1 dead, aliased)
  {
    int row = w;
    float4v x = *(const float4v*)(&nf32[row*260 + lane*4]);
    float s = x[0]+x[1]+x[2]+x[3];
    #pragma unroll
    for (int m=1;m<64;m<<=1) s += __shfl_xor(s,m,64);
    float mu = s * (1.f/256.f);
    float d0=x[0]-mu,d1=x[1]-mu,d2=x[2]-mu,d3=x[3]-mu;
    float vs=d0*d0+d1*d1+d2*d2+d3*d3;
    #pragma unroll
    for (int m=1;m<64;m<<=1) vs += __shfl_xor(vs,m,64);
    float rs = rsqrtf(vs*(1.f/256.f)+1e-5f);
    float4v gg = *(const float4v*)(lng + lane*4);
    float4v bb = *(const float4v*)(lnb + lane*4);
    short4v o;
    o[0]=(short)f2bf(d0*rs*gg[0]+bb[0]);
    o[1]=(short)f2bf(d1*rs*gg[1]+bb[1]);
    o[2]=(short)f2bf(d2*rs*gg[2]+bb[2]);
    o[3]=(short)f2bf(d3*rs*gg[3]+bb[3]);
    *(short4v*)(&sh[row*HLD + lane*4]) = o;
  }
  __syncthreads();
  // P GEMM: wave w -> packed tiles w*2, w*2+1
  float4v pc[2] = {};
  const short8* pb = (const short8*)W12p;
  for (int kt = 0; kt < 8; ++kt){
    short8 a0 = *(const short8*)(&sh[(size_t)l15*HLD + kt*32 + q*8]);
    #pragma unroll
    for (int i = 0; i < 2; ++i){
      short8 bfr = pb[(size_t)(kt*32 + w*2 + i)*64 + lane];
      pc[i] = MFMA16(a0, bfr, pc[i]);
    }
  }
  #pragma unroll
  for (int i = 0; i < 2; ++i){
    int nt = w*2 + i;
    unsigned short* dst = (nt < 16) ? P1 : P2;
    int ch = (nt & 15)*16 + l15;
    float lv = (nt < 16) ? lpwl[g*256 + ch] : 0.0f;
    #pragma unroll
    for (int r = 0; r < 4; ++r){
      int node = r0 + q*4 + r;
      dst[(size_t)node*256 + ch] = f2bf(pc[i][r] + lv);
    }
  }
}

// ---- final LN + graph mean + ALL output heads (256 blocks) ------------------
__global__ __launch_bounds__(256) void k_lnFO(
    const float* __restrict__ nf, const float* __restrict__ g_,
    const float* __restrict__ b_,
    const unsigned short* __restrict__ typep, const float* __restrict__ typeb,
    const unsigned short* __restrict__ polarp,
    const unsigned short* __restrict__ fracp,
    float* __restrict__ out)
{
  __shared__ unsigned short hld[33 * HLD];
  const int w = threadIdx.x >> 6, lane = threadIdx.x & 63;
  const int l15 = lane & 15, q = lane >> 4;
  const int g = blockIdx.x >> 1, h = blockIdx.x & 1;
  #pragma unroll
  for (int rr = 0; rr < 8; ++rr){
    int row = w * 8 + rr;
    float4v x = *(const float4v*)(nf + ((size_t)(g*32+row))*256 + lane*4);
    float s = x[0]+x[1]+x[2]+x[3];
    #pragma unroll
    for (int m=1;m<64;m<<=1) s += __shfl_xor(s,m,64);
    float mu = s * (1.f/256.f);
    float d0=x[0]-mu,d1=x[1]-mu,d2=x[2]-mu,d3=x[3]-mu;
    float vs=d0*d0+d1*d1+d2*d2+d3*d3;
    #pragma unroll
    for (int m=1;m<64;m<<=1) vs += __shfl_xor(vs,m,64);
    float rs = rsqrtf(vs*(1.f/256.f)+1e-5f);
    float4v gg = *(const float4v*)(g_ + lane*4);
    float4v bb = *(const float4v*)(b_ + lane*4);
    short4v o;
    o[0]=(short)f2bf(d0*rs*gg[0]+bb[0]);
    o[1]=(short)f2bf(d1*rs*gg[1]+bb[1]);
    o[2]=(short)f2bf(d2*rs*gg[2]+bb[2]);
    o[3]=(short)f2bf(d3*rs*gg[3]+bb[3]);
    *(short4v*)(&hld[row*HLD + lane*4]) = o;
  }
  __syncthreads();
  {
    int c = threadIdx.x;
    float s = 0.0f;
    #pragma unroll
    for (int n = 0; n < 32; ++n) s += bf2f(hld[n*HLD + c]);
    hld[32*HLD + c] = f2bf(s * (1.0f/32.0f));
  }
  __syncthreads();
  // type head: rows of m-tile h, 100 cols, K=256
  {
    float4v tacc[2] = {};
    const short8* pb = (const short8*)typep;
    for (int kt = 0; kt < 8; ++kt){
      short8 a0 = *(const short8*)(&hld[(size_t)(h*16 + l15)*HLD + kt*32 + q*8]);
      #pragma unroll
      for (int i = 0; i < 2; ++i){
        int nt = w + i*4; if (nt > 6) nt = 6;
        short8 bfr = pb[(size_t)(kt*7 + nt)*64 + lane];
        tacc[i] = MFMA16(a0, bfr, tacc[i]);
      }
    }
    #pragma unroll
    for (int i = 0; i < 2; ++i){
      int c = (w + i*4)*16 + l15;
      if (c < 100){
        float bv = typeb[c];
        #pragma unroll
        for (int r = 0; r < 4; ++r){
          int node = g*32 + h*16 + q*4 + r;
          out[(size_t)node*100 + c] = tacc[i][r] + bv;
        }
      }
    }
  }
  // frac head: rows of m-tile h; wave 0
  if (w == 0){
    float4v facc = {};
    const short8* pb = (const short8*)fracp;
    for (int kt = 0; kt < 8; ++kt){
      short8 a0 = *(const short8*)(&hld[(size_t)(h*16 + l15)*HLD + kt*32 + q*8]);
      facc = MFMA16(a0, pb[(size_t)kt*64 + lane], facc);
    }
    if (l15 < 3){
      #pragma unroll
      for (int r = 0; r < 4; ++r){
        int node = g*32 + h*16 + q*4 + r;
        out[410368 + (size_t)node*3 + l15] = facc[r];
      }
    }
  }
  // polar head: 1x6 from gf (hld row 32); h==1, wave 3
  if (h == 1 && w == 3){
    float4v pacc = {};
    const short8* pb = (const short8*)polarp;
    for (int kt = 0; kt < 8; ++kt){
      short8 a0 = *(const short8*)(&hld[(size_t)32*HLD + kt*32 + q*8]);
      pacc = MFMA16(a0, pb[(size_t)kt*64 + lane], pacc);
    }
    if (q == 0 && l15 < 6)
      out[409600 + (size_t)g*6 + l15] = pacc[0];
  }
}

// ---- fused edge kernel v14 (unchanged: 32 KiB swizzled M1, 5 blocks/CU) -----
#define M1SW(row, col) ((((row) << 8) + (col)) ^ (((row) & 7) << 3))
__global__ __launch_bounds__(256, 4) void k_edge(
    const unsigned short* __restrict__ femb,
    const unsigned short* __restrict__ W1botp,
    const unsigned short* __restrict__ P1,
    const unsigned short* __restrict__ P2,
    const unsigned short* __restrict__ W2Tp,
    const float* __restrict__ b2,
    unsigned short* __restrict__ cat2)
{
  __shared__ unsigned short M1[64 * 256];   // 32 KiB exactly
  const int w = threadIdx.x >> 6, lane = threadIdx.x & 63;
  const int l15 = lane & 15, q = lane >> 4;
  const int b = blockIdx.x, g = b >> 4;
  const int n0 = (b & 15) * 2;
  const int cb = w * 64;
  const short8* fb8  = (const short8*)femb;
  const short8* w1b8 = (const short8*)W1botp;
  const short8* w2t8 = (const short8*)W2Tp;

  short4v p1v[2][4], p2v[2][4];
  #pragma unroll
  for (int ct = 0; ct < 4; ++ct){
    int co = cb + ct*16 + q*4;
    p1v[0][ct] = *(const short4v*)(P1 + (size_t)(g*32 + n0    )*256 + co);
    p1v[1][ct] = *(const short4v*)(P1 + (size_t)(g*32 + n0 + 1)*256 + co);
    p2v[0][ct] = *(const short4v*)(P2 + (size_t)(g*32 +      l15)*256 + co);
    p2v[1][ct] = *(const short4v*)(P2 + (size_t)(g*32 + 16 + l15)*256 + co);
  }

  float4v acc[4][4] = {};
  #pragma unroll
  for (int ks = 0; ks < 2; ++ks){
    short8 a[4];
    #pragma unroll
    for (int ct = 0; ct < 4; ++ct)
      a[ct] = w1b8[(size_t)(ks * 16 + w * 4 + ct) * 64 + lane];
    #pragma unroll
    for (int et = 0; et < 4; ++et){
      short8 bf = fb8[((size_t)((b*4 + et)*2 + ks))*64 + lane];
      #pragma unroll
      for (int ct = 0; ct < 4; ++ct)
        acc[ct][et] = MFMA16(a[ct], bf, acc[ct][et]);
    }
  }
  #pragma unroll
  for (int ct = 0; ct < 4; ++ct)
    #pragma unroll
    for (int et = 0; et < 4; ++et){
      short4v sv;
      #pragma unroll
      for (int r = 0; r < 4; ++r){
        float v = acc[ct][et][r] + bf2f(p1v[et>>1][ct][r]) + bf2f(p2v[et&1][ct][r]);
        sv[r] = (short)f2bf(siluf(v));
      }
      *(short4v*)(&M1[M1SW(et * 16 + l15, cb + ct * 16 + q * 4)]) = sv;
    }
  __syncthreads();
  float4v c2[4][4] = {};
  for (int kt = 0; kt < 8; ++kt){
    short8 a[4];
    #pragma unroll
    for (int ct = 0; ct < 4; ++ct)
      a[ct] = w2t8[(size_t)(kt * 16 + w * 4 + ct) * 64 + lane];
    #pragma unroll
    for (int et = 0; et < 4; ++et){
      short8 m = *(const short8*)(&M1[M1SW(et * 16 + l15, kt * 32 + q * 8)]);
      #pragma unroll
      for (int ct = 0; ct < 4; ++ct)
        c2[ct][et] = MFMA16(m, a[ct], c2[ct][et]);
    }
  }
  #pragma unroll
  for (int ct = 0; ct < 4; ++ct){
    float bv = b2[cb + ct * 16 + l15];
    #pragma unroll
    for (int nn = 0; nn < 2; ++nn){
      float s = siluf(c2[ct][2*nn  ][0] + bv) + siluf(c2[ct][2*nn  ][1] + bv)
              + siluf(c2[ct][2*nn  ][2] + bv) + siluf(c2[ct][2*nn  ][3] + bv)
              + siluf(c2[ct][2*nn+1][0] + bv) + siluf(c2[ct][2*nn+1][1] + bv)
              + siluf(c2[ct][2*nn+1][2] + bv) + siluf(c2[ct][2*nn+1][3] + bv);
      s += __shfl_xor(s, 16, 64);
      s += __shfl_xor(s, 32, 64);
      if (q == 0)
        cat2[(size_t)(b*2 + nn) * 512 + 256 + cb + ct * 16 + l15] =
            f2bf(s * (1.0f / 32.0f));
    }
  }
}

// ---- launcher --------------------------------------------------------------
extern "C" void kernel_launch(void* const* d_in, const int* in_sizes, int n_in,
                              void* d_out, int out_size, void* d_ws, size_t ws_size,
                              hipStream_t stream)
{
  const float* t      = (const float*)d_in[0];
  const float* at     = (const float*)d_in[1];
  const float* fc     = (const float*)d_in[2];
  const float* lpol   = (const float*)d_in[3];
  const float* Ws     = (const float*)d_in[5];
  const float* bs     = (const float*)d_in[6];
  const float* Wn     = (const float*)d_in[7];
  const float* bn     = (const float*)d_in[8];
  const float* ln_g   = (const float*)d_in[9];
  const float* ln_b   = (const float*)d_in[10];
  const float* m1W    = (const float*)d_in[11];
  const float* m1b    = (const float*)d_in[12];
  const float* m2W    = (const float*)d_in[13];
  const float* m2b    = (const float*)d_in[14];
  const float* a1W    = (const float*)d_in[15];
  const float* a1b    = (const float*)d_in[16];
  const float* a2W    = (const float*)d_in[17];
  const float* a2b    = (const float*)d_in[18];
  const float* flng   = (const float*)d_in[19];
  const float* flnb   = (const float*)d_in[20];
  const float* typeW  = (const float*)d_in[21];
  const float* typeb  = (const float*)d_in[22];
  const float* polarW = (const float*)d_in[23];
  const float* fracW  = (const float*)d_in[24];
  float* out = (float*)d_out;

  char* ws = (char*)d_ws;
  size_t off = 0;
  auto alloc = [&](size_t bytes) -> char* {
    char* p = ws + off; off += (bytes + 255) & ~(size_t)255; return p;
  };
  float*          nf    = (float*)         alloc((size_t)4096*256*4);
  unsigned short* cat2  = (unsigned short*)alloc((size_t)4096*512*2);
  unsigned short* femb  = (unsigned short*)alloc((size_t)131072*64*2);
  float*          lpw   = (float*)         alloc((size_t)4*128*256*4);
  unsigned short* P1    = (unsigned short*)alloc((size_t)4096*256*2);
  unsigned short* P2    = (unsigned short*)alloc((size_t)4096*256*2);
  unsigned short* Wsp   = (unsigned short*)alloc((size_t)4*16*1024);
  unsigned short* Wnp   = (unsigned short*)alloc((size_t)12*16*1024);
  unsigned short* typep = (unsigned short*)alloc((size_t)8*7*1024);
  unsigned short* polarp= (unsigned short*)alloc((size_t)8*1*1024);
  unsigned short* fracp = (unsigned short*)alloc((size_t)8*1*1024);
  unsigned short* W12p  = (unsigned short*)alloc((size_t)4*131072*2);
  unsigned short* W1botp= (unsigned short*)alloc((size_t)4*16384*2);
  unsigned short* W2Tp  = (unsigned short*)alloc((size_t)4*65536*2);
  unsigned short* a1p   = (unsigned short*)alloc((size_t)4*131072*2);
  unsigned short* a2p   = (unsigned short*)alloc((size_t)4*65536*2);

  k_prep<<<dim3(1906), dim3(256), 0, stream>>>(Ws, Wn, typeW, polarW, fracW,
      m1W, m2W, a1W, a2W,
      Wsp, Wnp, typep, polarp, fracp, W12p, W1botp, W2Tp, a1p, a2p,
      fc, lpol, m1b, femb, lpw);
  // fused: pad-at + type_emb GEMM + nf0 GEMM + LN0 + P GEMM
  k_embed<<<dim3(256), dim3(1024), 0, stream>>>(at, t, Wsp, bs, Wnp, bn,
      ln_g, ln_b, W12p, lpw, nf, cat2, P1, P2);

  for (int l = 0; l < 4; ++l){
    int ln = (l + 1 < 4) ? l + 1 : 3;   // params valid; P-step skipped on l=3
    k_edge<<<dim3(2048), dim3(256), 0, stream>>>(femb, W1botp + (size_t)l*16384,
        P1, P2, W2Tp + (size_t)l*65536, m2b + l*256, cat2);
    k_a12P<<<dim3(256), dim3(1024), 0, stream>>>(cat2, a1p + (size_t)l*131072,
        a1b + l*256, a2p + (size_t)l*65536, a2b + l*256, nf, cat2,
        ln_g + ln*256, ln_b + ln*256, W12p + (size_t)ln*131072,
        lpw + (size_t)ln*32768, P1, P2, (l < 3) ? 1 : 0);
  }

  k_lnFO<<<dim3(256), dim3(256), 0, stream>>>(nf, flng, flnb,
      typep, typeb, polarp, fracp, out);
}

// Round 13
// 325.827 us; speedup vs baseline: 1.0107x; 1.0107x over previous
//
#include <hip/hip_runtime.h>
#include <hip/hip_bf16.h>

// ---- types / helpers -------------------------------------------------------
typedef __attribute__((ext_vector_type(8))) short short8;
typedef __attribute__((ext_vector_type(4))) short short4v;
typedef __attribute__((ext_vector_type(4))) float float4v;
typedef __bf16 bf16x8 __attribute__((ext_vector_type(8)));

#define MFMA16(A,B,C) __builtin_amdgcn_mfma_f32_16x16x32_bf16( \
    __builtin_bit_cast(bf16x8,(A)), __builtin_bit_cast(bf16x8,(B)), (C), 0, 0, 0)

static __device__ __forceinline__ float bf2f(unsigned short b){
  unsigned u = ((unsigned)b) << 16; float f; __builtin_memcpy(&f,&u,sizeof(f)); return f;
}
// native RNE convert: compiler emits v_cvt_pk_bf16_f32
static __device__ __forceinline__ unsigned short f2bf(float f){
  __bf16 h = (__bf16)f;
  return __builtin_bit_cast(unsigned short, h);
}
static __device__ __forceinline__ float siluf(float x){
  return x * __builtin_amdgcn_rcpf(1.0f + __expf(-x));
}
static __device__ __forceinline__ float ldf(const float* p, size_t i){ return p[i]; }
static __device__ __forceinline__ float ldf(const unsigned short* p, size_t i){ return bf2f(p[i]); }

// ---- weight packing into fragment order ------------------------------------
template<typename T>
static __device__ __forceinline__ void pack_tile(
    const T* W, int ldw, int Krows, int Ncols,
    unsigned short* dst, int NTtot, int ntoff, int kt, int nt,
    const float* addrow, int lane)
{
  int l15 = lane & 15, q = lane >> 4;
  int col = nt * 16 + l15;
  int kr0 = kt * 32 + q * 8;
  short8 v;
  #pragma unroll
  for (int j = 0; j < 8; ++j){
    int r = kr0 + j;
    float x = 0.0f;
    if (r < Krows && col < Ncols){
      x = ldf(W, (size_t)r * ldw + col);
      if (addrow) x += addrow[(r >> 5) * 256 + col];
    }
    v[j] = (short)f2bf(x);
  }
  ((short8*)dst)[(size_t)(kt * NTtot + ntoff + nt) * 64 + lane] = v;
}

static __device__ __forceinline__ void packW_dispatch(
    int b, int lane,
    const float* Ws, const float* Wn,
    const float* typeW, const float* polarW, const float* fracW,
    const float* m1W, const float* m2W, const float* a1W, const float* a2W,
    unsigned short* Wsp, unsigned short* Wnp, unsigned short* typep,
    unsigned short* polarp, unsigned short* fracp,
    unsigned short* W12p, unsigned short* W1botp, unsigned short* W2Tp,
    unsigned short* a1p, unsigned short* a2p)
{
  if (b < 64)      { pack_tile(Ws,    256, 100, 256, Wsp,   16, 0, b >> 4, b & 15, nullptr, lane); return; }
  if (b < 256){ int s = b - 64;  pack_tile(Wn,    256, 384, 256, Wnp,   16, 0, s >> 4, s & 15, nullptr, lane); return; }
  if (b < 312){ int s = b - 256; pack_tile(typeW, 100, 256, 100, typep,  7, 0, s / 7,  s % 7,  nullptr, lane); return; }
  if (b < 320){ int s = b - 312; pack_tile(polarW,  6, 256,   6, polarp, 1, 0, s, 0, nullptr, lane); return; }
  if (b < 328){ int s = b - 320; pack_tile(fracW,   3, 256,   3, fracp,  1, 0, s, 0, nullptr, lane); return; }
  int s2 = b - 328;                   // 3200 layer-pack tiles
  int l = s2 / 800, bb = s2 % 800;
  const float* m1Wl = m1W + (size_t)l * 578 * 256;
  const float* m2Wl = m2W + (size_t)l * 65536;
  const float* a1Wl = a1W + (size_t)l * 131072;
  const float* a2Wl = a2W + (size_t)l * 65536;
  unsigned short* W12pl   = W12p   + (size_t)l * 131072;
  unsigned short* W1botpl = W1botp + (size_t)l * 16384;
  unsigned short* W2Tpl   = W2Tp   + (size_t)l * 65536;
  unsigned short* a1pl    = a1p    + (size_t)l * 131072;
  unsigned short* a2pl    = a2p    + (size_t)l * 65536;
  if (bb < 128)       pack_tile(m1Wl,           256, 256, 256, W12pl,  32,  0, bb >> 4, bb & 15, nullptr, lane);
  else if (bb < 256){ int s = bb - 128; pack_tile(m1Wl + 256*256, 256, 256, 256, W12pl,  32, 16, s >> 4, s & 15, nullptr, lane); }
  else if (bb < 288){ int s = bb - 256; pack_tile(m1Wl + 512*256, 256,  64, 256, W1botpl,16,  0, s >> 4, s & 15, nullptr, lane); }
  else if (bb < 416){ int s = bb - 288; pack_tile(m2Wl,           256, 256, 256, W2Tpl,  16,  0, s >> 4, s & 15, nullptr, lane); }
  else if (bb < 672){ int s = bb - 416; pack_tile(a1Wl,           256, 512, 256, a1pl,   16,  0, s >> 4, s & 15, nullptr, lane); }
  else              { int s = bb - 672; pack_tile(a2Wl,           256, 256, 256, a2pl,   16,  0, s >> 4, s & 15, nullptr, lane); }
}

// ---- preprocessing: weight packing + femb + lpw -----------------------------
__global__ void k_prep(
    const float* Ws, const float* Wn,
    const float* typeW, const float* polarW, const float* fracW,
    const float* m1W, const float* m2W, const float* a1W, const float* a2W,
    unsigned short* Wsp, unsigned short* Wnp, unsigned short* typep,
    unsigned short* polarp, unsigned short* fracp,
    unsigned short* W12p, unsigned short* W1botp, unsigned short* W2Tp,
    unsigned short* a1p, unsigned short* a2p,
    const float* fc, const float* lpol, const float* m1b,
    unsigned short* femb, float* lpw)
{
  int b0 = blockIdx.x;
  if (b0 < 882){
    int tile = b0 * 4 + (threadIdx.x >> 6);
    packW_dispatch(tile, threadIdx.x & 63, Ws, Wn, typeW, polarW, fracW,
                   m1W, m2W, a1W, a2W, Wsp, Wnp, typep, polarp, fracp,
                   W12p, W1botp, W2Tp, a1p, a2p);
    return;
  }
  int b = b0 - 882;
  if (b < 512){
    int e = b * 256 + threadIdx.x;             // E = 131072
    int g = e >> 10, i = (e >> 5) & 31, j = e & 31;
    int nt = g * 32 + i, ns = g * 32 + j;
    unsigned short o[64];
    #pragma unroll
    for (int k = 0; k < 3; ++k){
      float d = fc[ns * 3 + k] - fc[nt * 3 + k];
      d -= floorf(d);
      #pragma unroll
      for (int f = 0; f < 10; ++f){
        float ang = d * (6.283185307179586f * (float)f);
        o[k * 10 + f]      = f2bf(__sinf(ang));
        o[30 + k * 10 + f] = f2bf(__cosf(ang));
      }
    }
    #pragma unroll
    for (int z = 60; z < 64; ++z) o[z] = 0;
    // fragment-block layout write (v11)
    short8* dst = (short8*)femb;
    int eb = e >> 4, l15e = e & 15;
    #pragma unroll
    for (int ks = 0; ks < 2; ++ks)
      #pragma unroll
      for (int qq = 0; qq < 4; ++qq){
        short8 s;
        #pragma unroll
        for (int j2 = 0; j2 < 8; ++j2) s[j2] = (short)o[(ks*4+qq)*8 + j2];
        dst[((size_t)(eb*2 + ks))*64 + qq*16 + l15e] = s;
      }
  } else {
    int s = b - 512;
    int l = s >> 7, g = s & 127, c = threadIdx.x;
    const float* W = m1W + (size_t)l * 578 * 256;
    float acc = m1b[l * 256 + c];
    #pragma unroll
    for (int k = 0; k < 6; ++k)
      acc += lpol[g * 6 + k] * W[(572 + k) * 256 + c];
    lpw[((size_t)l * 128 + g) * 256 + c] = acc;
  }
}

#define HLD 264   // LDS row stride (shorts) for 256-col bf16 tiles

// ---- fused embedding pipeline (v14 config: 256 thr / 4 waves) ---------------
__global__ __launch_bounds__(256) void k_embed(
    const float* __restrict__ at, const float* __restrict__ t,
    const unsigned short* __restrict__ Wsp, const float* __restrict__ bs,
    const unsigned short* __restrict__ Wnp, const float* __restrict__ bn,
    const float* __restrict__ lng, const float* __restrict__ lnb,
    const unsigned short* __restrict__ W12p, const float* __restrict__ lpwl,
    float* __restrict__ nf, unsigned short* __restrict__ cat2w,
    unsigned short* __restrict__ P1, unsigned short* __restrict__ P2)
{
  __shared__ unsigned short at_s[16 * 136];    // 4.4 KB
  __shared__ unsigned short cat1_s[16 * 392];  // 12.5 KB
  __shared__ float nf32[16 * 260];             // 16.6 KB
  __shared__ unsigned short sh[16 * HLD];      // 8.4 KB
  const int w = threadIdx.x >> 6, lane = threadIdx.x & 63;
  const int l15 = lane & 15, q = lane >> 4;
  const int r0 = blockIdx.x * 16, g = blockIdx.x >> 1;
  // stage at rows (bf16, pad to 128 cols); time emb -> cat1_s cols 256..383
  {
    int row = threadIdx.x & 15, c0 = (threadIdx.x >> 4) * 8;
    #pragma unroll
    for (int j = 0; j < 8; ++j){
      int c = c0 + j;
      at_s[row*136 + c] = (c < 100) ? f2bf(at[(size_t)(r0+row)*100 + c])
                                    : (unsigned short)0;
    }
    if (threadIdx.x < 128){
      int i = threadIdx.x;
      float tg = t[g];
      int f = i & 63;
      float fr = __expf((-9.210340371976184f / 63.0f) * (float)f);
      float arg = tg * fr;
      float v = (i < 64) ? __sinf(arg) : __cosf(arg);
      unsigned short hv = f2bf(v);
      for (int n = 0; n < 16; ++n) cat1_s[n*392 + 256 + i] = hv;
    }
  }
  __syncthreads();
  // GEMM1: te = at_pad @ Ws + bs -> cat1_s[:, 0:256]
  {
    float4v acc[4] = {};
    const short8* pb = (const short8*)Wsp;
    for (int kt = 0; kt < 4; ++kt){
      short8 a0 = *(const short8*)(&at_s[l15*136 + kt*32 + q*8]);
      #pragma unroll
      for (int i = 0; i < 4; ++i){
        short8 bfr = pb[(size_t)(kt*16 + w*4 + i)*64 + lane];
        acc[i] = MFMA16(a0, bfr, acc[i]);
      }
    }
    #pragma unroll
    for (int i = 0; i < 4; ++i){
      int c = (w*4+i)*16 + l15;
      float bv = bs[c];
      #pragma unroll
      for (int r = 0; r < 4; ++r)
        cat1_s[(q*4+r)*392 + c] = f2bf(acc[i][r] + bv);
    }
  }
  __syncthreads();
  // GEMM2: nf0 = cat1 @ Wn + bn -> nf (f32), cat2 left half, nf32 LDS
  {
    float4v acc[4] = {};
    const short8* pb = (const short8*)Wnp;
    for (int kt = 0; kt < 12; ++kt){
      short8 a0 = *(const short8*)(&cat1_s[l15*392 + kt*32 + q*8]);
      #pragma unroll
      for (int i = 0; i < 4; ++i){
        short8 bfr = pb[(size_t)(kt*16 + w*4 + i)*64 + lane];
        acc[i] = MFMA16(a0, bfr, acc[i]);
      }
    }
    #pragma unroll
    for (int i = 0; i < 4; ++i){
      int c = (w*4+i)*16 + l15;
      float bv = bn[c];
      #pragma unroll
      for (int r = 0; r < 4; ++r){
        int row = r0 + q*4 + r;
        float v = acc[i][r] + bv;
        nf[(size_t)row*256 + c] = v;
        cat2w[(size_t)row*512 + c] = f2bf(v);
        nf32[(q*4+r)*260 + c] = v;
      }
    }
  }
  __syncthreads();
  // LN layer-0 (wave w -> rows w*4..w*4+3) -> sh
  #pragma unroll
  for (int rr = 0; rr < 4; ++rr){
    int row = w * 4 + rr;
    float4v x = *(const float4v*)(&nf32[row*260 + lane*4]);
    float s = x[0]+x[1]+x[2]+x[3];
    #pragma unroll
    for (int m=1;m<64;m<<=1) s += __shfl_xor(s,m,64);
    float mu = s * (1.f/256.f);
    float d0=x[0]-mu,d1=x[1]-mu,d2=x[2]-mu,d3=x[3]-mu;
    float vs=d0*d0+d1*d1+d2*d2+d3*d3;
    #pragma unroll
    for (int m=1;m<64;m<<=1) vs += __shfl_xor(vs,m,64);
    float rs = rsqrtf(vs*(1.f/256.f)+1e-5f);
    float4v gg = *(const float4v*)(lng + lane*4);
    float4v bb = *(const float4v*)(lnb + lane*4);
    short4v o;
    o[0]=(short)f2bf(d0*rs*gg[0]+bb[0]);
    o[1]=(short)f2bf(d1*rs*gg[1]+bb[1]);
    o[2]=(short)f2bf(d2*rs*gg[2]+bb[2]);
    o[3]=(short)f2bf(d3*rs*gg[3]+bb[3]);
    *(short4v*)(&sh[row*HLD + lane*4]) = o;
  }
  __syncthreads();
  // P GEMM: [16 nodes] x [512 ch], K=256; wave w -> packed tiles w*8..w*8+7
  float4v pc[8] = {};
  const short8* pb = (const short8*)W12p;
  for (int kt = 0; kt < 8; ++kt){
    short8 a0 = *(const short8*)(&sh[(size_t)l15*HLD + kt*32 + q*8]);
    #pragma unroll
    for (int i = 0; i < 8; ++i){
      short8 bfr = pb[(size_t)(kt*32 + w*8 + i)*64 + lane];
      pc[i] = MFMA16(a0, bfr, pc[i]);
    }
  }
  #pragma unroll
  for (int i = 0; i < 8; ++i){
    int nt = w*8 + i;
    unsigned short* dst = (nt < 16) ? P1 : P2;
    int ch = (nt & 15)*16 + l15;
    float lv = (nt < 16) ? lpwl[g*256 + ch] : 0.0f;
    #pragma unroll
    for (int r = 0; r < 4; ++r){
      int node = r0 + q*4 + r;
      dst[(size_t)node*256 + ch] = f2bf(pc[i][r] + lv);
    }
  }
}

// ---- fused a1+a2 epilogue MLP + next-layer LN + P GEMM (v14 config: 8 waves)
__global__ __launch_bounds__(512) void k_a12P(
    const unsigned short* __restrict__ cat2,
    const unsigned short* __restrict__ a1pl, const float* __restrict__ a1bl,
    const unsigned short* __restrict__ a2pl, const float* __restrict__ a2bl,
    float* __restrict__ nf, unsigned short* __restrict__ cat2w,
    const float* __restrict__ lng, const float* __restrict__ lnb,
    const unsigned short* __restrict__ W12p, const float* __restrict__ lpwl,
    unsigned short* __restrict__ P1, unsigned short* __restrict__ P2, int doP)
{
  __shared__ float nf32[16 * 260];          // 16.6 KB (new nf rows, f32)
  __shared__ unsigned short sh[16 * HLD];   // 8.4 KB: t1, then LN'd h (aliased)
  const int w = threadIdx.x >> 6, lane = threadIdx.x & 63;
  const int l15 = lane & 15, q = lane >> 4;
  const int r0 = blockIdx.x * 16;
  const int g = blockIdx.x >> 1;
  const short8* pb1 = (const short8*)a1pl;
  const short8* pb2 = (const short8*)a2pl;
  // GEMM1: t1 = silu(cat2 @ a1W + b1); wave w -> col tiles w*2+{0,1}
  float4v acc[2] = {};
  for (int kt = 0; kt < 16; ++kt){
    short8 a0 = *(const short8*)(cat2 + (size_t)(r0 + l15)*512 + kt*32 + q*8);
    #pragma unroll
    for (int i = 0; i < 2; ++i){
      short8 bfr = pb1[(size_t)(kt*16 + w*2 + i)*64 + lane];
      acc[i] = MFMA16(a0, bfr, acc[i]);
    }
  }
  #pragma unroll
  for (int i = 0; i < 2; ++i){
    int c = (w*2+i)*16 + l15;
    float bv = a1bl[c];
    #pragma unroll
    for (int r = 0; r < 4; ++r)
      sh[(size_t)(q*4 + r)*HLD + c] = f2bf(siluf(acc[i][r] + bv));
  }
  __syncthreads();
  // GEMM2: c2 = t1 @ a2W; wave w -> col tiles w*2+{0,1}
  float4v c2[2] = {};
  for (int kt = 0; kt < 8; ++kt){
    short8 a0 = *(const short8*)(&sh[(size_t)l15*HLD + kt*32 + q*8]);
    #pragma unroll
    for (int i = 0; i < 2; ++i){
      short8 bfr = pb2[(size_t)(kt*16 + w*2 + i)*64 + lane];
      c2[i] = MFMA16(a0, bfr, c2[i]);
    }
  }
  // epilogue: v = nf + silu(c2 + b2); write nf (f32), cat2 left half, nf32 LDS
  #pragma unroll
  for (int i = 0; i < 2; ++i){
    int c = (w*2+i)*16 + l15;
    float bv = a2bl[c];
    #pragma unroll
    for (int r = 0; r < 4; ++r){
      int row = r0 + q*4 + r;
      float v = nf[(size_t)row*256 + c] + siluf(c2[i][r] + bv);
      nf[(size_t)row*256 + c] = v;
      cat2w[(size_t)row*512 + c] = f2bf(v);
      nf32[(q*4 + r)*260 + c] = v;
    }
  }
  if (!doP) return;
  __syncthreads();
  // LN_{l+1}: wave w -> rows w*2..w*2+1 -> sh (t1 dead, aliased)
  #pragma unroll
  for (int rr = 0; rr < 2; ++rr){
    int row = w * 2 + rr;
    float4v x = *(const float4v*)(&nf32[row*260 + lane*4]);
    float s = x[0]+x[1]+x[2]+x[3];
    #pragma unroll
    for (int m=1;m<64;m<<=1) s += __shfl_xor(s,m,64);
    float mu = s * (1.f/256.f);
    float d0=x[0]-mu,d1=x[1]-mu,d2=x[2]-mu,d3=x[3]-mu;
    float vs=d0*d0+d1*d1+d2*d2+d3*d3;
    #pragma unroll
    for (int m=1;m<64;m<<=1) vs += __shfl_xor(vs,m,64);
    float rs = rsqrtf(vs*(1.f/256.f)+1e-5f);
    float4v gg = *(const float4v*)(lng + lane*4);
    float4v bb = *(const float4v*)(lnb + lane*4);
    short4v o;
    o[0]=(short)f2bf(d0*rs*gg[0]+bb[0]);
    o[1]=(short)f2bf(d1*rs*gg[1]+bb[1]);
    o[2]=(short)f2bf(d2*rs*gg[2]+bb[2]);
    o[3]=(short)f2bf(d3*rs*gg[3]+bb[3]);
    *(short4v*)(&sh[row*HLD + lane*4]) = o;
  }
  __syncthreads();
  // P GEMM: [16 nodes] x [512 ch], K=256; wave w -> packed tiles w*4..w*4+3
  float4v pc[4] = {};
  const short8* pb = (const short8*)W12p;
  for (int kt = 0; kt < 8; ++kt){
    short8 a0 = *(const short8*)(&sh[(size_t)l15*HLD + kt*32 + q*8]);
    #pragma unroll
    for (int i = 0; i < 4; ++i){
      short8 bfr = pb[(size_t)(kt*32 + w*4 + i)*64 + lane];
      pc[i] = MFMA16(a0, bfr, pc[i]);
    }
  }
  #pragma unroll
  for (int i = 0; i < 4; ++i){
    int nt = w*4 + i;
    unsigned short* dst = (nt < 16) ? P1 : P2;
    int ch = (nt & 15)*16 + l15;
    float lv = (nt < 16) ? lpwl[g*256 + ch] : 0.0f;
    #pragma unroll
    for (int r = 0; r < 4; ++r){
      int node = r0 + q*4 + r;
      dst[(size_t)node*256 + ch] = f2bf(pc[i][r] + lv);
    }
  }
}

// ---- final LN + graph mean + ALL output heads (256 blocks) ------------------
__global__ __launch_bounds__(256) void k_lnFO(
    const float* __restrict__ nf, const float* __restrict__ g_,
    const float* __restrict__ b_,
    const unsigned short* __restrict__ typep, const float* __restrict__ typeb,
    const unsigned short* __restrict__ polarp,
    const unsigned short* __restrict__ fracp,
    float* __restrict__ out)
{
  __shared__ unsigned short hld[33 * HLD];
  const int w = threadIdx.x >> 6, lane = threadIdx.x & 63;
  const int l15 = lane & 15, q = lane >> 4;
  const int g = blockIdx.x >> 1, h = blockIdx.x & 1;
  #pragma unroll
  for (int rr = 0; rr < 8; ++rr){
    int row = w * 8 + rr;
    float4v x = *(const float4v*)(nf + ((size_t)(g*32+row))*256 + lane*4);
    float s = x[0]+x[1]+x[2]+x[3];
    #pragma unroll
    for (int m=1;m<64;m<<=1) s += __shfl_xor(s,m,64);
    float mu = s * (1.f/256.f);
    float d0=x[0]-mu,d1=x[1]-mu,d2=x[2]-mu,d3=x[3]-mu;
    float vs=d0*d0+d1*d1+d2*d2+d3*d3;
    #pragma unroll
    for (int m=1;m<64;m<<=1) vs += __shfl_xor(vs,m,64);
    float rs = rsqrtf(vs*(1.f/256.f)+1e-5f);
    float4v gg = *(const float4v*)(g_ + lane*4);
    float4v bb = *(const float4v*)(b_ + lane*4);
    short4v o;
    o[0]=(short)f2bf(d0*rs*gg[0]+bb[0]);
    o[1]=(short)f2bf(d1*rs*gg[1]+bb[1]);
    o[2]=(short)f2bf(d2*rs*gg[2]+bb[2]);
    o[3]=(short)f2bf(d3*rs*gg[3]+bb[3]);
    *(short4v*)(&hld[row*HLD + lane*4]) = o;
  }
  __syncthreads();
  {
    int c = threadIdx.x;
    float s = 0.0f;
    #pragma unroll
    for (int n = 0; n < 32; ++n) s += bf2f(hld[n*HLD + c]);
    hld[32*HLD + c] = f2bf(s * (1.0f/32.0f));
  }
  __syncthreads();
  // type head: rows of m-tile h, 100 cols, K=256
  {
    float4v tacc[2] = {};
    const short8* pb = (const short8*)typep;
    for (int kt = 0; kt < 8; ++kt){
      short8 a0 = *(const short8*)(&hld[(size_t)(h*16 + l15)*HLD + kt*32 + q*8]);
      #pragma unroll
      for (int i = 0; i < 2; ++i){
        int nt = w + i*4; if (nt > 6) nt = 6;
        short8 bfr = pb[(size_t)(kt*7 + nt)*64 + lane];
        tacc[i] = MFMA16(a0, bfr, tacc[i]);
      }
    }
    #pragma unroll
    for (int i = 0; i < 2; ++i){
      int c = (w + i*4)*16 + l15;
      if (c < 100){
        float bv = typeb[c];
        #pragma unroll
        for (int r = 0; r < 4; ++r){
          int node = g*32 + h*16 + q*4 + r;
          out[(size_t)node*100 + c] = tacc[i][r] + bv;
        }
      }
    }
  }
  // frac head: rows of m-tile h; wave 0
  if (w == 0){
    float4v facc = {};
    const short8* pb = (const short8*)fracp;
    for (int kt = 0; kt < 8; ++kt){
      short8 a0 = *(const short8*)(&hld[(size_t)(h*16 + l15)*HLD + kt*32 + q*8]);
      facc = MFMA16(a0, pb[(size_t)kt*64 + lane], facc);
    }
    if (l15 < 3){
      #pragma unroll
      for (int r = 0; r < 4; ++r){
        int node = g*32 + h*16 + q*4 + r;
        out[410368 + (size_t)node*3 + l15] = facc[r];
      }
    }
  }
  // polar head: 1x6 from gf (hld row 32); h==1, wave 3
  if (h == 1 && w == 3){
    float4v pacc = {};
    const short8* pb = (const short8*)polarp;
    for (int kt = 0; kt < 8; ++kt){
      short8 a0 = *(const short8*)(&hld[(size_t)32*HLD + kt*32 + q*8]);
      pacc = MFMA16(a0, pb[(size_t)kt*64 + lane], pacc);
    }
    if (q == 0 && l15 < 6)
      out[409600 + (size_t)g*6 + l15] = pacc[0];
  }
}

// ---- fused edge kernel v14 (unchanged: 32 KiB swizzled M1, 5 blocks/CU) -----
#define M1SW(row, col) ((((row) << 8) + (col)) ^ (((row) & 7) << 3))
__global__ __launch_bounds__(256, 4) void k_edge(
    const unsigned short* __restrict__ femb,
    const unsigned short* __restrict__ W1botp,
    const unsigned short* __restrict__ P1,
    const unsigned short* __restrict__ P2,
    const unsigned short* __restrict__ W2Tp,
    const float* __restrict__ b2,
    unsigned short* __restrict__ cat2)
{
  __shared__ unsigned short M1[64 * 256];   // 32 KiB exactly
  const int w = threadIdx.x >> 6, lane = threadIdx.x & 63;
  const int l15 = lane & 15, q = lane >> 4;
  const int b = blockIdx.x, g = b >> 4;
  const int n0 = (b & 15) * 2;
  const int cb = w * 64;
  const short8* fb8  = (const short8*)femb;
  const short8* w1b8 = (const short8*)W1botp;
  const short8* w2t8 = (const short8*)W2Tp;

  short4v p1v[2][4], p2v[2][4];
  #pragma unroll
  for (int ct = 0; ct < 4; ++ct){
    int co = cb + ct*16 + q*4;
    p1v[0][ct] = *(const short4v*)(P1 + (size_t)(g*32 + n0    )*256 + co);
    p1v[1][ct] = *(const short4v*)(P1 + (size_t)(g*32 + n0 + 1)*256 + co);
    p2v[0][ct] = *(const short4v*)(P2 + (size_t)(g*32 +      l15)*256 + co);
    p2v[1][ct] = *(const short4v*)(P2 + (size_t)(g*32 + 16 + l15)*256 + co);
  }

  float4v acc[4][4] = {};
  #pragma unroll
  for (int ks = 0; ks < 2; ++ks){
    short8 a[4];
    #pragma unroll
    for (int ct = 0; ct < 4; ++ct)
      a[ct] = w1b8[(size_t)(ks * 16 + w * 4 + ct) * 64 + lane];
    #pragma unroll
    for (int et = 0; et < 4; ++et){
      short8 bf = fb8[((size_t)((b*4 + et)*2 + ks))*64 + lane];
      #pragma unroll
      for (int ct = 0; ct < 4; ++ct)
        acc[ct][et] = MFMA16(a[ct], bf, acc[ct][et]);
    }
  }
  #pragma unroll
  for (int ct = 0; ct < 4; ++ct)
    #pragma unroll
    for (int et = 0; et < 4; ++et){
      short4v sv;
      #pragma unroll
      for (int r = 0; r < 4; ++r){
        float v = acc[ct][et][r] + bf2f(p1v[et>>1][ct][r]) + bf2f(p2v[et&1][ct][r]);
        sv[r] = (short)f2bf(siluf(v));
      }
      *(short4v*)(&M1[M1SW(et * 16 + l15, cb + ct * 16 + q * 4)]) = sv;
    }
  __syncthreads();
  float4v c2[4][4] = {};
  for (int kt = 0; kt < 8; ++kt){
    short8 a[4];
    #pragma unroll
    for (int ct = 0; ct < 4; ++ct)
      a[ct] = w2t8[(size_t)(kt * 16 + w * 4 + ct) * 64 + lane];
    #pragma unroll
    for (int et = 0; et < 4; ++et){
      short8 m = *(const short8*)(&M1[M1SW(et * 16 + l15, kt * 32 + q * 8)]);
      #pragma unroll
      for (int ct = 0; ct < 4; ++ct)
        c2[ct][et] = MFMA16(m, a[ct], c2[ct][et]);
    }
  }
  #pragma unroll
  for (int ct = 0; ct < 4; ++ct){
    float bv = b2[cb + ct * 16 + l15];
    #pragma unroll
    for (int nn = 0; nn < 2; ++nn){
      float s = siluf(c2[ct][2*nn  ][0] + bv) + siluf(c2[ct][2*nn  ][1] + bv)
              + siluf(c2[ct][2*nn  ][2] + bv) + siluf(c2[ct][2*nn  ][3] + bv)
              + siluf(c2[ct][2*nn+1][0] + bv) + siluf(c2[ct][2*nn+1][1] + bv)
              + siluf(c2[ct][2*nn+1][2] + bv) + siluf(c2[ct][2*nn+1][3] + bv);
      s += __shfl_xor(s, 16, 64);
      s += __shfl_xor(s, 32, 64);
      if (q == 0)
        cat2[(size_t)(b*2 + nn) * 512 + 256 + cb + ct * 16 + l15] =
            f2bf(s * (1.0f / 32.0f));
    }
  }
}

// ---- launcher --------------------------------------------------------------
extern "C" void kernel_launch(void* const* d_in, const int* in_sizes, int n_in,
                              void* d_out, int out_size, void* d_ws, size_t ws_size,
                              hipStream_t stream)
{
  const float* t      = (const float*)d_in[0];
  const float* at     = (const float*)d_in[1];
  const float* fc     = (const float*)d_in[2];
  const float* lpol   = (const float*)d_in[3];
  const float* Ws     = (const float*)d_in[5];
  const float* bs     = (const float*)d_in[6];
  const float* Wn     = (const float*)d_in[7];
  const float* bn     = (const float*)d_in[8];
  const float* ln_g   = (const float*)d_in[9];
  const float* ln_b   = (const float*)d_in[10];
  const float* m1W    = (const float*)d_in[11];
  const float* m1b    = (const float*)d_in[12];
  const float* m2W    = (const float*)d_in[13];
  const float* m2b    = (const float*)d_in[14];
  const float* a1W    = (const float*)d_in[15];
  const float* a1b    = (const float*)d_in[16];
  const float* a2W    = (const float*)d_in[17];
  const float* a2b    = (const float*)d_in[18];
  const float* flng   = (const float*)d_in[19];
  const float* flnb   = (const float*)d_in[20];
  const float* typeW  = (const float*)d_in[21];
  const float* typeb  = (const float*)d_in[22];
  const float* polarW = (const float*)d_in[23];
  const float* fracW  = (const float*)d_in[24];
  float* out = (float*)d_out;

  char* ws = (char*)d_ws;
  size_t off = 0;
  auto alloc = [&](size_t bytes) -> char* {
    char* p = ws + off; off += (bytes + 255) & ~(size_t)255; return p;
  };
  float*          nf    = (float*)         alloc((size_t)4096*256*4);
  unsigned short* cat2  = (unsigned short*)alloc((size_t)4096*512*2);
  unsigned short* femb  = (unsigned short*)alloc((size_t)131072*64*2);
  float*          lpw   = (float*)         alloc((size_t)4*128*256*4);
  unsigned short* P1    = (unsigned short*)alloc((size_t)4096*256*2);
  unsigned short* P2    = (unsigned short*)alloc((size_t)4096*256*2);
  unsigned short* Wsp   = (unsigned short*)alloc((size_t)4*16*1024);
  unsigned short* Wnp   = (unsigned short*)alloc((size_t)12*16*1024);
  unsigned short* typep = (unsigned short*)alloc((size_t)8*7*1024);
  unsigned short* polarp= (unsigned short*)alloc((size_t)8*1*1024);
  unsigned short* fracp = (unsigned short*)alloc((size_t)8*1*1024);
  unsigned short* W12p  = (unsigned short*)alloc((size_t)4*131072*2);
  unsigned short* W1botp= (unsigned short*)alloc((size_t)4*16384*2);
  unsigned short* W2Tp  = (unsigned short*)alloc((size_t)4*65536*2);
  unsigned short* a1p   = (unsigned short*)alloc((size_t)4*131072*2);
  unsigned short* a2p   = (unsigned short*)alloc((size_t)4*65536*2);

  k_prep<<<dim3(1906), dim3(256), 0, stream>>>(Ws, Wn, typeW, polarW, fracW,
      m1W, m2W, a1W, a2W,
      Wsp, Wnp, typep, polarp, fracp, W12p, W1botp, W2Tp, a1p, a2p,
      fc, lpol, m1b, femb, lpw);
  // fused: pad-at + type_emb GEMM + nf0 GEMM + LN0 + P GEMM
  k_embed<<<dim3(256), dim3(256), 0, stream>>>(at, t, Wsp, bs, Wnp, bn,
      ln_g, ln_b, W12p, lpw, nf, cat2, P1, P2);

  for (int l = 0; l < 4; ++l){
    int ln = (l + 1 < 4) ? l + 1 : 3;   // params valid; P-step skipped on l=3
    k_edge<<<dim3(2048), dim3(256), 0, stream>>>(femb, W1botp + (size_t)l*16384,
        P1, P2, W2Tp + (size_t)l*65536, m2b + l*256, cat2);
    k_a12P<<<dim3(256), dim3(512), 0, stream>>>(cat2, a1p + (size_t)l*131072,
        a1b + l*256, a2p + (size_t)l*65536, a2b + l*256, nf, cat2,
        ln_g + ln*256, ln_b + ln*256, W12p + (size_t)ln*131072,
        lpw + (size_t)ln*32768, P1, P2, (l < 3) ? 1 : 0);
  }

  k_lnFO<<<dim3(256), dim3(256), 0, stream>>>(nf, flng, flnb,
      typep, typeb, polarp, fracp, out);
}